// Round 5
// baseline (3167.042 us; speedup 1.0000x reference)
//
#include <hip/hip_runtime.h>

// Problem constants
#define D     512
#define KK    8          // modules per batch
#define SS    4          // workspace slots
#define GB    4          // batches per block (main kernel)
#define BTOT  8192
#define SCALE 0.04419417382415922f   // 512^-0.5
#define LN_EPS 1e-5f
#define FSTR  516        // fp32 LDS row stride (floats): 2064B, 16B-aligned rows

// ---- module-scope device scratch (no d_ws dependence; fully rewritten every launch) ----
__device__ int   g_flag;
__device__ float g_qw[SS * D];
__device__ float g_aq[SS * D];
__device__ float g_mr[D * D];   // Wq_r^T Wk_r, fp32 row-major [d][d']
__device__ float g_mo[D * D];   // Wo Wv_r,     fp32 row-major [e][d]

__device__ __forceinline__ float wred(float v){
  #pragma unroll
  for (int m = 1; m < 64; m <<= 1) v += __shfl_xor(v, m, 64);
  return v;
}

// ---------- K0: Qw[s,e] = sum_d slots[s,d]*Wq_w[e,d]  + mask-layout flag ----------
__global__ void k0_qw_flag(const float* __restrict__ wq_w, const float* __restrict__ slots,
                           const void* __restrict__ mask){
  int tid = threadIdx.x;
  if (blockIdx.x == 0){
    __shared__ int f;
    if (tid == 0) f = 0;
    __syncthreads();
    if (tid < 256){
      const unsigned char* mb = (const unsigned char*)mask;
      int nz = mb[tid*4+1] | mb[tid*4+2] | mb[tid*4+3];
      if (nz) atomicOr(&f, 1);        // any nonzero off-word byte => u8/bool layout
    }
    __syncthreads();
    if (tid == 0) g_flag = f;
  }
  int w = tid >> 6, l = tid & 63;
  int gw = blockIdx.x * 8 + w;                  // 32 waves total
  for (int i = 0; i < 64; ++i){                 // 64 dots per wave
    int dI = gw * 64 + i;
    int s = dI >> 9, e = dI & 511;
    const float* a = slots + s * D + l * 8;
    const float* b = wq_w  + e * D + l * 8;
    float acc = 0.f;
    #pragma unroll
    for (int j = 0; j < 8; ++j) acc += a[j] * b[j];
    acc = wred(acc);
    if (l == 0) g_qw[s * D + e] = acc;
  }
}

// ---------- K1: Aq[s,d] = sum_e Qw[s,e]*Wk_w[e,d] ----------
__global__ void k1_aq(const float* __restrict__ wk_w){
  int s = blockIdx.x, d = threadIdx.x;
  float a0 = 0.f, a1 = 0.f, a2 = 0.f, a3 = 0.f;
  for (int e = 0; e < D; e += 4){
    a0 += g_qw[s * D + e + 0] * wk_w[(e + 0) * D + d];
    a1 += g_qw[s * D + e + 1] * wk_w[(e + 1) * D + d];
    a2 += g_qw[s * D + e + 2] * wk_w[(e + 2) * D + d];
    a3 += g_qw[s * D + e + 3] * wk_w[(e + 3) * D + d];
  }
  g_aq[s * D + d] = (a0 + a1) + (a2 + a3);
}

// ---------- K2: composed DxD matrices, fp32 row-major ----------
// mode 0: g_mr[r][c] = sum_i P[i][r]*Q[i][c]   (Wq_r^T Wk_r)
// mode 1: g_mo[r][c] = sum_i P[r][i]*Q[i][c]   (Wo Wv_r)
__global__ void k2_mm(const float* __restrict__ P, const float* __restrict__ Q, int mode){
  float* dst = (mode == 0) ? g_mr : g_mo;
  int c = blockIdx.x * 64 + (threadIdx.x & 63);
  int r = blockIdx.y * 4 + (threadIdx.x >> 6);
  float acc = 0.f;
  if (mode == 0){ for (int i = 0; i < D; ++i) acc += P[i * D + r] * Q[i * D + c]; }
  else          { for (int i = 0; i < D; ++i) acc += P[r * D + i] * Q[i * D + c]; }
  dst[r * D + c] = acc;
}

// ---------- K4: fused main, GB=4, pure fp32 (bisect: no bf16, no MFMA anywhere) ----------
// Vector GEMM scheme (all 3 GEMMs): out[16][512] = A(16x512, LDS) @ W^T(global row-major W[col][c]).
// wave w -> rows r0=(w&3)*4..+4, col-half ch=w>>2; lane -> cols ch*256 + lane*4 + j (j<4).
__global__ __launch_bounds__(512, 4)
void k4_main(const float* __restrict__ hidden, const void* __restrict__ maskp,
             const float* __restrict__ slots, const float* __restrict__ wv_w,
             const float* __restrict__ gws, const float* __restrict__ bws,
             const float* __restrict__ gout, const float* __restrict__ bout,
             float* __restrict__ out){
  __shared__ __align__(16) float mixBuf[16 * FSTR];  // h_mix -> t -> v
  __shared__ __align__(16) float wsBuf[16 * FSTR];   // ws_upd (persistent GEMM2+3)
  __shared__ float attw[128];                        // [bl][s][k]
  __shared__ float attr[128];                        // [bl][k][s]
  __shared__ float part1[32], part2[32];             // LN partials [ch][row]

  const int tid = threadIdx.x;
  const int w = tid >> 6, lane = tid & 63;
  const int r0 = (w & 3) * 4;                        // wave's 4 GEMM rows
  const int ch = w >> 2;                             // wave's col-half
  const int cb = ch * 256 + lane * 4;                // lane's first col
  const int b0 = blockIdx.x * GB;
  const size_t gbase = (size_t)b0 * KK * D;

  // ---- P1: write-attn softmax (waves 0..3, wave = batch), all fp32 ----
  if (w < 4){
    int flag = g_flag;
    unsigned mbits = 0;
    const int gb = b0 + w;
    if (flag){
      const unsigned char* m8 = (const unsigned char*)maskp;
      #pragma unroll
      for (int k = 0; k < KK; ++k) mbits |= (m8[gb * KK + k] ? 1u : 0u) << k;
    } else {
      const int* m32 = (const int*)maskp;
      #pragma unroll
      for (int k = 0; k < KK; ++k) mbits |= (m32[gb * KK + k] ? 1u : 0u) << k;
    }
    #pragma unroll
    for (int s = 0; s < SS; ++s){
      const float* ap = g_aq + s * D + lane * 8;
      float a0 = ap[0], a1 = ap[1], a2 = ap[2], a3 = ap[3];
      float a4 = ap[4], a5 = ap[5], a6 = ap[6], a7 = ap[7];
      float lg[KK];
      #pragma unroll
      for (int k = 0; k < KK; ++k){
        const float* hp = hidden + gbase + (size_t)(w * KK + k) * D + lane * 8;
        float4 h0 = *(const float4*)hp;
        float4 h1 = *(const float4*)(hp + 4);
        float p = a0*h0.x + a1*h0.y + a2*h0.z + a3*h0.w
                + a4*h1.x + a5*h1.y + a6*h1.z + a7*h1.w;
        p = wred(p) * SCALE;
        lg[k] = ((mbits >> k) & 1u) ? p : -3.0e38f;
      }
      float mx = -3.0e38f;
      #pragma unroll
      for (int k = 0; k < KK; ++k) mx = fmaxf(mx, lg[k]);
      float pe[KK]; float sum = 0.f;
      #pragma unroll
      for (int k = 0; k < KK; ++k){ pe[k] = (lg[k] > -1e38f) ? __expf(lg[k] - mx) : 0.f; sum += pe[k]; }
      float inv = (sum > 0.f) ? 1.f / sum : 0.f;   // all-masked -> zeros (nan_to_num)
      if (lane == 0){
        #pragma unroll
        for (int k = 0; k < KK; ++k) attw[(w * SS + s) * KK + k] = pe[k] * inv;
      }
    }
  }
  __syncthreads();

  // ---- P2: h_mix = attn_w @ hidden (fp32) -> mixBuf ----
  {
    #pragma unroll
    for (int i = 0; i < 2; ++i){
      int chunk = i * 512 + tid;                // 1024 chunks of 8
      int row = chunk >> 6;                     // 0..15 = bl*4+s
      int c8 = (chunk & 63) * 8;
      int bl = row >> 2, s = row & 3;
      float acc[8] = {0,0,0,0,0,0,0,0};
      #pragma unroll
      for (int k = 0; k < KK; ++k){
        float a = attw[(bl * SS + s) * KK + k];
        const float* hp = hidden + gbase + (size_t)(bl * KK + k) * D + c8;
        float4 h0 = *(const float4*)hp;
        float4 h1 = *(const float4*)(hp + 4);
        acc[0] += a*h0.x; acc[1] += a*h0.y; acc[2] += a*h0.z; acc[3] += a*h0.w;
        acc[4] += a*h1.x; acc[5] += a*h1.y; acc[6] += a*h1.z; acc[7] += a*h1.w;
      }
      float4 o0 = {acc[0], acc[1], acc[2], acc[3]};
      float4 o1 = {acc[4], acc[5], acc[6], acc[7]};
      *(float4*)(mixBuf + row * FSTR + c8) = o0;
      *(float4*)(mixBuf + row * FSTR + c8 + 4) = o1;
    }
  }
  __syncthreads();

  // ---- GEMM1: x = h_mix @ Wv_w^T + slots; LN -> wsBuf (ws_upd), all fp32 ----
  {
    float4 acc[4];
    #pragma unroll
    for (int r = 0; r < 4; ++r) acc[r] = (float4){0.f,0.f,0.f,0.f};
    const float* W0 = wv_w + (size_t)(cb + 0) * D;
    const float* W1 = wv_w + (size_t)(cb + 1) * D;
    const float* W2 = wv_w + (size_t)(cb + 2) * D;
    const float* W3 = wv_w + (size_t)(cb + 3) * D;
    for (int c4 = 0; c4 < 128; ++c4){
      float4 wv0 = ((const float4*)W0)[c4];
      float4 wv1 = ((const float4*)W1)[c4];
      float4 wv2 = ((const float4*)W2)[c4];
      float4 wv3 = ((const float4*)W3)[c4];
      #pragma unroll
      for (int r = 0; r < 4; ++r){
        float4 av = *(const float4*)(mixBuf + (r0 + r) * FSTR + c4 * 4);
        acc[r].x += av.x*wv0.x + av.y*wv0.y + av.z*wv0.z + av.w*wv0.w;
        acc[r].y += av.x*wv1.x + av.y*wv1.y + av.z*wv1.z + av.w*wv1.w;
        acc[r].z += av.x*wv2.x + av.y*wv2.y + av.z*wv2.z + av.w*wv2.w;
        acc[r].w += av.x*wv3.x + av.y*wv3.y + av.z*wv3.z + av.w*wv3.w;
      }
    }
    // x = proj + slots ; per-row LN partials (deterministic two-part combine)
    float x[4][4];
    #pragma unroll
    for (int r = 0; r < 4; ++r){
      int s = (r0 + r) & 3;
      float4 sl = *(const float4*)(slots + s * D + cb);
      x[r][0] = acc[r].x + sl.x; x[r][1] = acc[r].y + sl.y;
      x[r][2] = acc[r].z + sl.z; x[r][3] = acc[r].w + sl.w;
      float s1 = (x[r][0] + x[r][1]) + (x[r][2] + x[r][3]);
      float s2 = (x[r][0]*x[r][0] + x[r][1]*x[r][1]) + (x[r][2]*x[r][2] + x[r][3]*x[r][3]);
      s1 = wred(s1); s2 = wred(s2);
      if (lane == 0){ part1[ch * 16 + r0 + r] = s1; part2[ch * 16 + r0 + r] = s2; }
    }
    __syncthreads();                            // parts ready; mixBuf reads complete
    #pragma unroll
    for (int r = 0; r < 4; ++r){
      int row = r0 + r;
      float S1 = part1[row] + part1[16 + row];
      float S2 = part2[row] + part2[16 + row];
      float mu = S1 * (1.f / D);
      float rs = rsqrtf(S2 * (1.f / D) - mu * mu + LN_EPS);
      float4 g4 = *(const float4*)(gws + cb);
      float4 b4 = *(const float4*)(bws + cb);
      float4 o;
      o.x = (x[r][0] - mu) * rs * g4.x + b4.x;
      o.y = (x[r][1] - mu) * rs * g4.y + b4.y;
      o.z = (x[r][2] - mu) * rs * g4.z + b4.z;
      o.w = (x[r][3] - mu) * rs * g4.w + b4.w;
      *(float4*)(wsBuf + row * FSTR + cb) = o;
    }
  }
  __syncthreads();                              // ws_upd complete

  // ---- GEMM2: t = SCALE*(ws_upd @ Mr^T) -> mixBuf (fp32) ----
  {
    float4 acc[4];
    #pragma unroll
    for (int r = 0; r < 4; ++r) acc[r] = (float4){0.f,0.f,0.f,0.f};
    const float* W0 = g_mr + (size_t)(cb + 0) * D;
    const float* W1 = g_mr + (size_t)(cb + 1) * D;
    const float* W2 = g_mr + (size_t)(cb + 2) * D;
    const float* W3 = g_mr + (size_t)(cb + 3) * D;
    for (int c4 = 0; c4 < 128; ++c4){
      float4 wv0 = ((const float4*)W0)[c4];
      float4 wv1 = ((const float4*)W1)[c4];
      float4 wv2 = ((const float4*)W2)[c4];
      float4 wv3 = ((const float4*)W3)[c4];
      #pragma unroll
      for (int r = 0; r < 4; ++r){
        float4 av = *(const float4*)(wsBuf + (r0 + r) * FSTR + c4 * 4);
        acc[r].x += av.x*wv0.x + av.y*wv0.y + av.z*wv0.z + av.w*wv0.w;
        acc[r].y += av.x*wv1.x + av.y*wv1.y + av.z*wv1.z + av.w*wv1.w;
        acc[r].z += av.x*wv2.x + av.y*wv2.y + av.z*wv2.z + av.w*wv2.w;
        acc[r].w += av.x*wv3.x + av.y*wv3.y + av.z*wv3.z + av.w*wv3.w;
      }
    }
    #pragma unroll
    for (int r = 0; r < 4; ++r){
      float4 o = {acc[r].x * SCALE, acc[r].y * SCALE, acc[r].z * SCALE, acc[r].w * SCALE};
      *(float4*)(mixBuf + (r0 + r) * FSTR + cb) = o;
    }
  }
  __syncthreads();                              // t ready

  // ---- P5: read-attn softmax over s (fp32 hidden x fp32 t) ----
  {
    int bl = w >> 1, kb = (w & 1) * 4;
    #pragma unroll
    for (int kk = 0; kk < 4; ++kk){
      int k = kb + kk;
      const float* hp = hidden + gbase + (size_t)(bl * KK + k) * D + lane * 8;
      float4 h0 = *(const float4*)hp;
      float4 h1 = *(const float4*)(hp + 4);
      float hx[8] = {h0.x,h0.y,h0.z,h0.w,h1.x,h1.y,h1.z,h1.w};
      float lg[SS];
      #pragma unroll
      for (int s = 0; s < SS; ++s){
        const float* tp = mixBuf + (bl * SS + s) * FSTR + lane * 8;
        float4 t0 = *(const float4*)tp;
        float4 t1 = *(const float4*)(tp + 4);
        float p = hx[0]*t0.x + hx[1]*t0.y + hx[2]*t0.z + hx[3]*t0.w
                + hx[4]*t1.x + hx[5]*t1.y + hx[6]*t1.z + hx[7]*t1.w;
        lg[s] = wred(p);                        // t already carries SCALE
      }
      float mx = fmaxf(fmaxf(lg[0], lg[1]), fmaxf(lg[2], lg[3]));
      float pe[SS]; float sum = 0.f;
      #pragma unroll
      for (int s = 0; s < SS; ++s){ pe[s] = __expf(lg[s] - mx); sum += pe[s]; }
      float inv = 1.f / sum;
      if (lane == 0){
        #pragma unroll
        for (int s = 0; s < SS; ++s) attr[(bl * KK + k) * SS + s] = pe[s] * inv;
      }
    }
  }
  __syncthreads();                              // t consumed

  // ---- GEMM3: v = ws_upd @ Mo^T -> mixBuf (fp32) ----
  {
    float4 acc[4];
    #pragma unroll
    for (int r = 0; r < 4; ++r) acc[r] = (float4){0.f,0.f,0.f,0.f};
    const float* W0 = g_mo + (size_t)(cb + 0) * D;
    const float* W1 = g_mo + (size_t)(cb + 1) * D;
    const float* W2 = g_mo + (size_t)(cb + 2) * D;
    const float* W3 = g_mo + (size_t)(cb + 3) * D;
    for (int c4 = 0; c4 < 128; ++c4){
      float4 wv0 = ((const float4*)W0)[c4];
      float4 wv1 = ((const float4*)W1)[c4];
      float4 wv2 = ((const float4*)W2)[c4];
      float4 wv3 = ((const float4*)W3)[c4];
      #pragma unroll
      for (int r = 0; r < 4; ++r){
        float4 av = *(const float4*)(wsBuf + (r0 + r) * FSTR + c4 * 4);
        acc[r].x += av.x*wv0.x + av.y*wv0.y + av.z*wv0.z + av.w*wv0.w;
        acc[r].y += av.x*wv1.x + av.y*wv1.y + av.z*wv1.z + av.w*wv1.w;
        acc[r].z += av.x*wv2.x + av.y*wv2.y + av.z*wv2.z + av.w*wv2.w;
        acc[r].w += av.x*wv3.x + av.y*wv3.y + av.z*wv3.z + av.w*wv3.w;
      }
    }
    __syncthreads();                            // all P5 t-reads done before overwrite
    #pragma unroll
    for (int r = 0; r < 4; ++r)
      *(float4*)(mixBuf + (r0 + r) * FSTR + cb) = acc[r];
  }
  __syncthreads();                              // v ready

  // ---- P6: out = LN(hidden + sum_s p_s * v_s), fp32 ----
  {
    #pragma unroll
    for (int i = 0; i < 4; ++i){
      int row = w * 4 + i;                      // flat = bl*8+k
      int bl = row >> 3;
      float p0 = attr[row * SS + 0], p1 = attr[row * SS + 1];
      float p2 = attr[row * SS + 2], p3 = attr[row * SS + 3];
      float x[8]; float s1 = 0.f, s2 = 0.f;
      #pragma unroll
      for (int j2 = 0; j2 < 2; ++j2){
        int col = j2 * 256 + lane * 4;
        float4 hv = *(const float4*)(hidden + gbase + (size_t)row * D + col);
        float4 v0 = *(const float4*)(mixBuf + (bl * SS + 0) * FSTR + col);
        float4 v1 = *(const float4*)(mixBuf + (bl * SS + 1) * FSTR + col);
        float4 v2 = *(const float4*)(mixBuf + (bl * SS + 2) * FSTR + col);
        float4 v3 = *(const float4*)(mixBuf + (bl * SS + 3) * FSTR + col);
        float hx[4] = {hv.x, hv.y, hv.z, hv.w};
        float vx0[4] = {v0.x, v0.y, v0.z, v0.w};
        float vx1[4] = {v1.x, v1.y, v1.z, v1.w};
        float vx2[4] = {v2.x, v2.y, v2.z, v2.w};
        float vx3[4] = {v3.x, v3.y, v3.z, v3.w};
        #pragma unroll
        for (int j = 0; j < 4; ++j){
          float xv = hx[j] + p0*vx0[j] + p1*vx1[j] + p2*vx2[j] + p3*vx3[j];
          x[j2 * 4 + j] = xv; s1 += xv; s2 += xv * xv;
        }
      }
      s1 = wred(s1); s2 = wred(s2);
      float mu = s1 * (1.f / D);
      float rs = rsqrtf(s2 * (1.f / D) - mu * mu + LN_EPS);
      #pragma unroll
      for (int j2 = 0; j2 < 2; ++j2){
        int col = j2 * 256 + lane * 4;
        float4 g  = *(const float4*)(gout + col);
        float4 bb = *(const float4*)(bout + col);
        float4 o;
        o.x = (x[j2*4+0] - mu) * rs * g.x + bb.x;
        o.y = (x[j2*4+1] - mu) * rs * g.y + bb.y;
        o.z = (x[j2*4+2] - mu) * rs * g.z + bb.z;
        o.w = (x[j2*4+3] - mu) * rs * g.w + bb.w;
        *(float4*)(out + gbase + (size_t)row * D + col) = o;
      }
    }
  }
}

extern "C" void kernel_launch(void* const* d_in, const int* in_sizes, int n_in,
                              void* d_out, int out_size, void* d_ws, size_t ws_size,
                              hipStream_t stream){
  const float* hidden = (const float*)d_in[0];
  const void*  mask   = d_in[1];
  const float* slots  = (const float*)d_in[2];
  const float* wq_w   = (const float*)d_in[3];
  const float* wk_w   = (const float*)d_in[4];
  const float* wv_w   = (const float*)d_in[5];
  const float* wq_r   = (const float*)d_in[6];
  const float* wk_r   = (const float*)d_in[7];
  const float* wv_r   = (const float*)d_in[8];
  const float* wo     = (const float*)d_in[9];
  const float* g_ws_  = (const float*)d_in[10];
  const float* b_ws_  = (const float*)d_in[11];
  const float* g_out_ = (const float*)d_in[12];
  const float* b_out_ = (const float*)d_in[13];

  hipLaunchKernelGGL(k0_qw_flag, dim3(4), dim3(512), 0, stream, wq_w, slots, mask);
  hipLaunchKernelGGL(k1_aq,      dim3(4), dim3(512), 0, stream, wk_w);
  hipLaunchKernelGGL(k2_mm,      dim3(8,128), dim3(256), 0, stream, wq_r, wk_r, 0);
  hipLaunchKernelGGL(k2_mm,      dim3(8,128), dim3(256), 0, stream, wo,   wv_r, 1);

  hipLaunchKernelGGL(k4_main, dim3(BTOT / GB), dim3(512), 0, stream,
                     hidden, mask, slots, wv_w, g_ws_, b_ws_, g_out_, b_out_, (float*)d_out);
}